// Round 2
// baseline (122.648 us; speedup 1.0000x reference)
//
#include <hip/hip_runtime.h>

#define BATCH 16384
#define DIM   512
#define UNITS 1024
// GAMMA = 0.5 folded: out = exp(cross - 0.5*xsq - 0.5*musq)

typedef float v16f __attribute__((ext_vector_type(16)));
#define MFMA_F8(a, b, c) __builtin_amdgcn_mfma_f32_32x32x16_fp8_fp8((a), (b), (c), 0, 0, 0)

__device__ __forceinline__ int2 cvt8(const float4 f0, const float4 f1) {
    int lo = __builtin_amdgcn_cvt_pk_fp8_f32(f0.x, f0.y, 0, false);
    lo     = __builtin_amdgcn_cvt_pk_fp8_f32(f0.z, f0.w, lo, true);
    int hi = __builtin_amdgcn_cvt_pk_fp8_f32(f1.x, f1.y, 0, false);
    hi     = __builtin_amdgcn_cvt_pk_fp8_f32(f1.z, f1.w, hi, true);
    return make_int2(lo, hi);
}
__device__ __forceinline__ float dot8(const float4 f0, const float4 f1) {
    return f0.x * f0.x + f0.y * f0.y + f0.z * f0.z + f0.w * f0.w
         + f1.x * f1.x + f1.y * f1.y + f1.z * f1.z + f1.w * f1.w;
}

// Fused RBF kernel, 512 blocks x 512 threads (8 waves), 2 blocks/CU.
// Block tile 256M x 128N. Grid: xcd = b&7, j = b>>3; mt = xcd*8 + (j&7),
// nt = j>>3 -> the 8 blocks sharing an m-tile all sit on one XCD (L2-local A).
// LDS 73.5 KB: Bs 64 KB (full B-tile, fp8 fragment order) + As 2x4 KB chunk
// dbuf + musq reductions; xsq reductions alias over dead Bs after the loop.
// Main loop: 32 chunks of 16 k, 2-deep register prefetch of A, 1 barrier/chunk.
__global__ __launch_bounds__(512, 4)
void rbf_fused_kernel(const float* __restrict__ in, const float* __restrict__ mu,
                      float* __restrict__ out) {
    __shared__ __attribute__((aligned(16))) unsigned char smem[75264];
    unsigned char* Bs = smem;                    // [4 ng][32 kw][64 l][8] fp8
    unsigned char* As = smem + 65536;            // 2 x [8 rg][64 l][8] fp8
    float* musq_red = (float*)(smem + 73728);    // [128][2]
    float* musq_l   = (float*)(smem + 74752);    // [128]
    // Aliased over Bs AFTER the main loop (Bs dead then):
    float* xsq_red  = (float*)smem;              // [256][2]
    float* xsq_l    = (float*)(smem + 2048);     // [256]

    const int t  = threadIdx.x;
    const int l  = t & 63;
    const int w  = t >> 6;          // wave 0..7
    const int ln = l & 31;
    const int h  = l >> 5;

    const int b   = blockIdx.x;     // 0..511
    const int xcd = b & 7;
    const int j   = b >> 3;         // 0..63
    const int m0  = (xcd * 8 + (j & 7)) * 256;
    const int n0  = (j >> 3) * 128;
    const int wm  = (w >> 1) * 64;  // 4 m positions
    const int wn  = (w & 1) * 64;   // 2 n positions

    // ---- A staging role: thread owns row ar, 8-float segment seg ----
    const int ar = t >> 1, seg = t & 1;
    const float* arow = in + (size_t)(m0 + ar) * DIM + seg * 8;
    // Fragment slot: lane (seg*32 + ar&31) of row-group rg = ar>>5.
    const int aidx = (((ar >> 5) * 64) + seg * 32 + (ar & 31)) * 8;

    // Prefetch chunks 0,1 (latency hides under phase B).
    float4 ga[2][2];
    ga[0][0] = ((const float4*)arow)[0];
    ga[0][1] = ((const float4*)arow)[1];
    ga[1][0] = ((const float4*)(arow + 16))[0];
    ga[1][1] = ((const float4*)(arow + 16))[1];

    // ---- Phase B: mu -> fp8 fragments in LDS + musq partials ----
    {
        const int ng  = w >> 1;             // 0..3 column group (32 cols)
        const int kwb = (w & 1) * 16;       // k-half (16 kws)
        const float* msrc = mu + (size_t)(kwb * 16 + h * 8) * UNITS + n0 + ng * 32 + ln;
        unsigned char* bdst = Bs + (((ng * 32 + kwb) * 64) + l) * 8;
        float s = 0.f;
#pragma unroll 4
        for (int kk = 0; kk < 16; kk++) {
            float v[8];
#pragma unroll
            for (int jj = 0; jj < 8; jj++) v[jj] = msrc[(size_t)(kk * 16 + jj) * UNITS];
#pragma unroll
            for (int jj = 0; jj < 8; jj++) s += v[jj] * v[jj];
            int lo = __builtin_amdgcn_cvt_pk_fp8_f32(v[0], v[1], 0, false);
            lo     = __builtin_amdgcn_cvt_pk_fp8_f32(v[2], v[3], lo, true);
            int hi = __builtin_amdgcn_cvt_pk_fp8_f32(v[4], v[5], 0, false);
            hi     = __builtin_amdgcn_cvt_pk_fp8_f32(v[6], v[7], hi, true);
            *(int2*)(bdst + kk * 512) = make_int2(lo, hi);
        }
        s += __shfl_xor(s, 32, 64);         // combine the two 8-k halves (h)
        if (h == 0) musq_red[(ng * 32 + ln) * 2 + (w & 1)] = s;
    }

    // Stage chunk 0 + start xsq accumulation.
    float sA = dot8(ga[0][0], ga[0][1]);
    *(int2*)(As + aidx) = cvt8(ga[0][0], ga[0][1]);
    __syncthreads();
    if (t < 128) musq_l[t] = -0.5f * (musq_red[t * 2] + musq_red[t * 2 + 1]);

    // ---- Main loop: 32 chunks x 4 MFMA, As dbuf, 2-deep reg prefetch ----
    const long* BsL = (const long*)Bs;
    v16f acc[2][2];
#pragma unroll
    for (int c = 0; c < 2; c++)
#pragma unroll
        for (int g = 0; g < 2; g++) acc[c][g] = (v16f)0.f;

#pragma unroll 2
    for (int i = 0; i < 32; i++) {
        if (i < 30) {                        // load chunk i+2 (regs just freed)
            ga[i & 1][0] = ((const float4*)(arow + (i + 2) * 16))[0];
            ga[i & 1][1] = ((const float4*)(arow + (i + 2) * 16))[1];
        }
        const long* AsL = (const long*)(As + (i & 1) * 4096);
        long a0 = AsL[((w >> 1) * 2 + 0) * 64 + l];
        long a1 = AsL[((w >> 1) * 2 + 1) * 64 + l];
        long b0 = BsL[(((w & 1) * 2 + 0) * 32 + i) * 64 + l];
        long b1 = BsL[(((w & 1) * 2 + 1) * 32 + i) * 64 + l];
        acc[0][0] = MFMA_F8(a0, b0, acc[0][0]);
        acc[0][1] = MFMA_F8(a0, b1, acc[0][1]);
        acc[1][0] = MFMA_F8(a1, b0, acc[1][0]);
        acc[1][1] = MFMA_F8(a1, b1, acc[1][1]);
        if (i < 31) {                        // stage chunk i+1 into other buf
            sA += dot8(ga[(i + 1) & 1][0], ga[(i + 1) & 1][1]);
            *(int2*)(As + ((i + 1) & 1) * 4096 + aidx)
                = cvt8(ga[(i + 1) & 1][0], ga[(i + 1) & 1][1]);
        }
        __syncthreads();
    }

    // ---- xsq reduction (aliased over dead Bs) ----
    xsq_red[ar * 2 + seg] = sA;
    __syncthreads();
    if (t < 256)
        xsq_l[t] = -0.5f * (xsq_red[t * 2] + xsq_red[t * 2 + 1]);
    __syncthreads();

    // ---- Epilogue: exp + nontemporal store.
    // C/D layout: col = l&31, row = (r&3) + 8*(r>>2) + 4*h. ----
#pragma unroll
    for (int c = 0; c < 2; c++) {
        const size_t mrow = m0 + wm + c * 32;
#pragma unroll
        for (int g = 0; g < 2; g++) {
            const int nc = n0 + wn + g * 32;
            const float mb = musq_l[wn + g * 32 + ln];
#pragma unroll
            for (int r = 0; r < 16; r++) {
                const int rl = (r & 3) + 8 * (r >> 2) + 4 * h;
                const float xb = xsq_l[wm + c * 32 + rl];
                float v = __expf(acc[c][g][r] + xb + mb);
                __builtin_nontemporal_store(
                    v, out + (mrow + rl) * UNITS + nc + ln);
            }
        }
    }
}

extern "C" void kernel_launch(void* const* d_in, const int* in_sizes, int n_in,
                              void* d_out, int out_size, void* d_ws, size_t ws_size,
                              hipStream_t stream) {
    const float* inputs = (const float*)d_in[0];   // [16384, 512] fp32
    const float* mu     = (const float*)d_in[1];   // [512, 1024] fp32
    float* out = (float*)d_out;                    // [16384, 1024] fp32
    (void)d_ws; (void)ws_size;                     // no workspace needed

    rbf_fused_kernel<<<512, 512, 0, stream>>>(inputs, mu, out);
}